// Round 6
// baseline (373.985 us; speedup 1.0000x reference)
//
#include <hip/hip_runtime.h>
#include <math.h>

#define B_      16
#define NH      32
#define NKV     8
#define HD      128
#define GQ      4
#define LWIN    4096
#define BS      16
#define MAXB    385
#define HIDDEN  4096
#define QKV_COLS 6144
#define TAB_N   4100
#define T_CUR   4080      // window index of the current (new) token
#define KS      64        // k-rows per gemm split slice
#define NSPLIT  64        // number of k slices (4096/KS)
#define NCHUNK  16        // 256-token chunks
#define SCALE   0.088388347648318447f   // 128^-0.5
#define LOG1E4  9.210340371976184
#define TWO_PI  6.283185307179586
#define INV_2PI 0.15915494309189535

typedef float f4v __attribute__((ext_vector_type(4)));
typedef float f2v __attribute__((ext_vector_type(2)));

// ---------------- K0: trig tables + zero patched blocks ----------------
__global__ void k_table(float* __restrict__ ctab, float* __restrict__ stab,
                        float* __restrict__ pk, float* __restrict__ pv) {
  int idx = blockIdx.x * 256 + threadIdx.x;
  if (idx < 64 * (TAB_N / 4)) {
    int d = idx / (TAB_N / 4);
    int q = idx - d * (TAB_N / 4);
    int i0 = q * 4;
    double f = exp(-(double)d / 64.0 * LOG1E4);
    double a = (double)(i0 - 1) * f;
    double rev = a * INV_2PI;
    rev -= rint(rev);
    float r = (float)(rev * TWO_PI);
    float c = cosf(r), s = sinf(r);
    float ff = (float)f;
    float cf = cosf(ff), sf = sinf(ff);
    int base = d * TAB_N + i0;
    ctab[base] = c; stab[base] = s;
#pragma unroll
    for (int j = 1; j < 4; j++) {
      float cn = c * cf - s * sf;
      float sn = s * cf + c * sf;
      c = cn; s = sn;
      ctab[base + j] = c; stab[base + j] = s;
    }
  }
  int nz = B_ * NKV * HD * BS;
  for (int z = idx; z < nz; z += gridDim.x * 256) { pk[z] = 0.f; pv[z] = 0.f; }
}

// ---------------- split-K skinny GEMM partial: part[ky][b][n] ----------------
__global__ __launch_bounds__(256) void k_gemm_part(
    const float* __restrict__ X, const float* __restrict__ W,
    float* __restrict__ part, int K, int ncols) {
  int tid = threadIdx.x;
  int k0 = blockIdx.y * KS;
  int n2 = (blockIdx.x * 256 + tid) * 2;
  f2v acc[B_];
#pragma unroll
  for (int b = 0; b < B_; b++) acc[b] = (f2v){0.f, 0.f};
  const float* wp = W + (size_t)k0 * ncols + n2;
  const float* xp = X + k0;
#pragma unroll 8
  for (int kk = 0; kk < KS; kk++) {
    f2v w = __builtin_nontemporal_load((const f2v*)&wp[(size_t)kk * ncols]);
#pragma unroll
    for (int b = 0; b < B_; b++) {
      float x = xp[b * K + kk];
      acc[b][0] = fmaf(x, w[0], acc[b][0]);
      acc[b][1] = fmaf(x, w[1], acc[b][1]);
    }
  }
  float* pp = part + (size_t)blockIdx.y * B_ * ncols + n2;
#pragma unroll
  for (int b = 0; b < B_; b++) *(f2v*)&pp[(size_t)b * ncols] = acc[b];
}

// ------------- reduce qkv partials + RoPE + scatter q / patched k,v -------------
__global__ __launch_bounds__(256) void k_qkv_finish(
    const float* __restrict__ part, const int* __restrict__ positions,
    const float* __restrict__ ctab, const float* __restrict__ stab,
    float* __restrict__ qout, float* __restrict__ pk, float* __restrict__ pv) {
  int idx = blockIdx.x * 256 + threadIdx.x;
  int b = idx / 3584;
  int u = idx - b * 3584;
  if (b >= B_) return;
  if (u < 2560) {                       // rope pair units: h in [0,40), j in [0,64)
    int h = u >> 6, j = u & 63;
    int c1 = h * 128 + j;
    int c2 = c1 + 64;
    float s1 = 0.f, s2 = 0.f;
#pragma unroll 8
    for (int ky = 0; ky < NSPLIT; ky++) {
      const float* p = part + ((size_t)ky * B_ + b) * QKV_COLS;
      s1 += p[c1];
      s2 += p[c2];
    }
    int pos = min(positions[b], LWIN - 1);
    float c = ctab[j * TAB_N + pos + 1];
    float s = stab[j * TAB_N + pos + 1];
    float o1 = s1 * c - s2 * s;
    float o2 = s2 * c + s1 * s;
    if (h < NH) {
      qout[b * HIDDEN + c1] = o1;
      qout[b * HIDDEN + c2] = o2;
    } else {
      int kv = h - NH;
      pk[((b * NKV + kv) * HD + j) * BS] = o1;
      pk[((b * NKV + kv) * HD + j + 64) * BS] = o2;
    }
  } else {                              // v units
    int vi = u - 2560;
    int kv = vi >> 7, d = vi & 127;
    int col = 5120 + vi;
    float s = 0.f;
#pragma unroll 8
    for (int ky = 0; ky < NSPLIT; ky++)
      s += part[((size_t)ky * B_ + b) * QKV_COLS + col];
    pv[((b * NKV + kv) * HD + d) * BS] = s;
  }
}

// ---------------- paged attention: 128-thread block per (pair, 256-token chunk) ----------------
// d-split: wave0 handles rotation pairs j in [0,32), wave1 j in [32,64); halves
// summed via LDS. 2048 blocks x 2 waves = 16 waves/CU.
__global__ __launch_bounds__(128) void k_attn(
    const float* __restrict__ kc, const float* __restrict__ vc,
    const int* __restrict__ bt, const float* __restrict__ qbuf,
    const float* __restrict__ pk, const float* __restrict__ pv,
    const float* __restrict__ ctab, const float* __restrict__ stab,
    float* __restrict__ partial) {
  __shared__ __align__(16) float qT[HD][GQ];      // [d][g]
  __shared__ __align__(16) float p_s[256][GQ];    // chunk-local probs
  __shared__ __align__(16) float scs[64][17];     // wave1 partial scores (padded)
  __shared__ const float* kbase[16];
  __shared__ const float* vbase[16];

  int bx = blockIdx.x;
  int b = bx & 15, kv = bx >> 4;
  int chunk = blockIdx.y;   // 0..15, 256 tokens each
  int tid = threadIdx.x;
  int lane = tid & 63, wave = tid >> 6;

  for (int i = tid; i < GQ * HD; i += 128) {
    int g = i >> 7, d = i & 127;
    qT[d][g] = qbuf[b * HIDDEN + (kv * GQ + g) * HD + d];
  }
  if (tid < 16) {
    int tb = chunk * 16 + tid;          // global 16-token block index
    if (tb == 255) {
      kbase[tid] = pk + (size_t)(b * NKV + kv) * (HD * BS);
      vbase[tid] = pv + (size_t)(b * NKV + kv) * (HD * BS);
    } else {
      int lg = (tb == 0) ? 0 : (129 + tb);
      size_t off = ((size_t)bt[b * MAXB + lg] * NKV + kv) * (HD * BS);
      kbase[tid] = kc + off;
      vbase[tid] = vc + off;
    }
  }
  __syncthreads();

  // ---- phase A: partial scores over this wave's 32 rotation pairs ----
  int blk_i = lane & 15, qq = lane >> 4;
  int t0 = chunk * 256 + blk_i * 16 + qq * 4;  // first of this lane's 4 tokens
  const float* kb = kbase[blk_i] + qq * 4;
  bool rot = (t0 >= 16) && (t0 < T_CUR);
  const float* ctp = ctab + t0;
  const float* stp = stab + t0;

  float sc[GQ][4];
#pragma unroll
  for (int g = 0; g < GQ; g++)
#pragma unroll
    for (int c = 0; c < 4; c++) sc[g][c] = 0.f;

  int dbase = wave * 32;
#pragma unroll 4
  for (int dd = 0; dd < 32; dd++) {
    int d = dbase + dd;
    f4v k1 = __builtin_nontemporal_load((const f4v*)(kb + d * BS));
    f4v k2 = __builtin_nontemporal_load((const f4v*)(kb + (d + 64) * BS));
    float4 cv = *(const float4*)(ctp + d * TAB_N);
    float4 sv = *(const float4*)(stp + d * TAB_N);
    float4 q1 = *(const float4*)&qT[d][0];
    float4 q2 = *(const float4*)&qT[d + 64][0];
    float cc[4] = {rot ? cv.x : 1.f, rot ? cv.y : 1.f, rot ? cv.z : 1.f, rot ? cv.w : 1.f};
    float ss[4] = {rot ? sv.x : 0.f, rot ? sv.y : 0.f, rot ? sv.z : 0.f, rot ? sv.w : 0.f};
    float qg1[4] = {q1.x, q1.y, q1.z, q1.w};
    float qg2[4] = {q2.x, q2.y, q2.z, q2.w};
#pragma unroll
    for (int c = 0; c < 4; c++) {
      float r1 = k1[c] * cc[c] - k2[c] * ss[c];
      float r2 = k2[c] * cc[c] + k1[c] * ss[c];
#pragma unroll
      for (int g = 0; g < GQ; g++)
        sc[g][c] = fmaf(qg1[g], r1, fmaf(qg2[g], r2, sc[g][c]));
    }
  }

  // ---- cross-wave half-sum: wave1 -> LDS, wave0 accumulates ----
  if (wave == 1) {
#pragma unroll
    for (int g = 0; g < GQ; g++)
#pragma unroll
      for (int c = 0; c < 4; c++) scs[lane][g * 4 + c] = sc[g][c];
  }
  __syncthreads();

  float mb[GQ];
  float ls[GQ];
  if (wave == 0) {
#pragma unroll
    for (int g = 0; g < GQ; g++)
#pragma unroll
      for (int c = 0; c < 4; c++) sc[g][c] += scs[lane][g * 4 + c];

    // scale + validity mask + chunk max (over 256 tokens = whole wave)
#pragma unroll
    for (int g = 0; g < GQ; g++) {
      float m = -3e38f;
#pragma unroll
      for (int c = 0; c < 4; c++) {
        float s = (t0 + c <= T_CUR) ? sc[g][c] * SCALE : -3e38f;
        sc[g][c] = s;
        m = fmaxf(m, s);
      }
#pragma unroll
      for (int off = 1; off < 64; off <<= 1) m = fmaxf(m, __shfl_xor(m, off, 64));
      mb[g] = m;
    }

    // probs + chunk sums
    float4 prc[4];
#pragma unroll
    for (int g = 0; g < GQ; g++) ls[g] = 0.f;
#pragma unroll
    for (int c = 0; c < 4; c++) {
      float p0 = __expf(sc[0][c] - mb[0]);
      float p1 = __expf(sc[1][c] - mb[1]);
      float p2 = __expf(sc[2][c] - mb[2]);
      float p3 = __expf(sc[3][c] - mb[3]);
      ls[0] += p0; ls[1] += p1; ls[2] += p2; ls[3] += p3;
      prc[c] = make_float4(p0, p1, p2, p3);
    }
#pragma unroll
    for (int g = 0; g < GQ; g++) {
      float v = ls[g];
#pragma unroll
      for (int off = 1; off < 64; off <<= 1) v += __shfl_xor(v, off, 64);
      ls[g] = v;
    }
    int trow = blk_i * 16 + qq * 4;
#pragma unroll
    for (int c = 0; c < 4; c++) *(float4*)&p_s[trow + c][0] = prc[c];
  }

  int pid = b * NKV + kv;
  float* pw = partial + ((size_t)pid * NCHUNK + chunk) * (GQ * 130);
  if (tid == 0) {
#pragma unroll
    for (int g = 0; g < GQ; g++) {
      pw[g * 130 + 0] = mb[g];
      pw[g * 130 + 1] = ls[g];
    }
  }
  __syncthreads();   // p_s ready

  // ---- phase B: PV, 64B/lane coalesced V reads, no barriers ----
  float acc0 = 0.f, acc1 = 0.f, acc2 = 0.f, acc3 = 0.f;
  int d_own = tid;   // 0..127
#pragma unroll 2
  for (int tb = 0; tb < 16; tb++) {
    const float* vb = vbase[tb] + d_own * BS;
    f4v v0 = __builtin_nontemporal_load((const f4v*)(vb));
    f4v v1 = __builtin_nontemporal_load((const f4v*)(vb + 4));
    f4v v2 = __builtin_nontemporal_load((const f4v*)(vb + 8));
    f4v v3 = __builtin_nontemporal_load((const f4v*)(vb + 12));
    float vv[16] = {v0[0], v0[1], v0[2], v0[3], v1[0], v1[1], v1[2], v1[3],
                    v2[0], v2[1], v2[2], v2[3], v3[0], v3[1], v3[2], v3[3]};
    const float* pp = &p_s[tb * 16][0];
#pragma unroll
    for (int j = 0; j < 16; j++) {
      float4 pj = *(const float4*)(pp + j * GQ);
      acc0 = fmaf(pj.x, vv[j], acc0);
      acc1 = fmaf(pj.y, vv[j], acc1);
      acc2 = fmaf(pj.z, vv[j], acc2);
      acc3 = fmaf(pj.w, vv[j], acc3);
    }
  }

  pw[0 * 130 + 2 + d_own] = acc0;
  pw[1 * 130 + 2 + d_own] = acc1;
  pw[2 * 130 + 2 + d_own] = acc2;
  pw[3 * 130 + 2 + d_own] = acc3;
}

// ---------------- combine chunk partials -> attn[b][h*128+d] ----------------
__global__ __launch_bounds__(512) void k_attn_combine(
    const float* __restrict__ partial, float* __restrict__ attn) {
  int pair = blockIdx.x;
  int tid = threadIdx.x;
  int g = tid >> 7, d = tid & 127;
  const float* pb = partial + (size_t)pair * NCHUNK * (GQ * 130) + g * 130;
  float M = -3e38f;
#pragma unroll
  for (int c = 0; c < NCHUNK; c++) M = fmaxf(M, pb[c * (GQ * 130)]);
  float L = 0.f, val = 0.f;
#pragma unroll
  for (int c = 0; c < NCHUNK; c++) {
    float m = pb[c * (GQ * 130)];
    float l = pb[c * (GQ * 130) + 1];
    float a = pb[c * (GQ * 130) + 2 + d];
    float w = __expf(m - M);
    L += l * w;
    val = fmaf(a, w, val);
  }
  int b = pair >> 3, kv = pair & 7;
  attn[b * HIDDEN + (kv * GQ + g) * HD + d] = val / L;
}

// ---------------- reduce w_o partials -> out ----------------
__global__ __launch_bounds__(256) void k_reduce_out(
    const float* __restrict__ part, float* __restrict__ out) {
  int idx = blockIdx.x * 256 + threadIdx.x;
  int b = idx >> 12, n = idx & 4095;
  float s = 0.f;
#pragma unroll 8
  for (int ky = 0; ky < NSPLIT; ky++)
    s += part[((size_t)ky * B_ + b) * HIDDEN + n];
  out[idx] = s;
}

extern "C" void kernel_launch(void* const* d_in, const int* in_sizes, int n_in,
                              void* d_out, int out_size, void* d_ws, size_t ws_size,
                              hipStream_t stream) {
  const int*   positions = (const int*)d_in[0];
  const float* hs        = (const float*)d_in[1];
  const float* kc        = (const float*)d_in[2];
  const float* vc        = (const float*)d_in[3];
  const int*   bt        = (const int*)d_in[4];
  const float* w_qkv     = (const float*)d_in[6];
  const float* w_o       = (const float*)d_in[7];
  float* out = (float*)d_out;

  float* ws    = (float*)d_ws;
  float* ctab  = ws;                    // 262400
  float* stab  = ctab + 262400;         // 262400
  float* pk    = stab + 262400;         // 262144
  float* pv    = pk + 262144;           // 262144
  float* qbuf  = pv + 262144;           // 65536
  float* apart = qbuf + 65536;          // 128*16*4*130 = 1064960
  float* attn  = apart + 1064960;       // 65536
  float* gpart = attn + 65536;          // 64*16*6144 = 6291456

  k_table<<<257, 256, 0, stream>>>(ctab, stab, pk, pv);
  k_gemm_part<<<dim3(QKV_COLS / 512, NSPLIT), 256, 0, stream>>>(hs, w_qkv, gpart, HIDDEN, QKV_COLS);
  k_qkv_finish<<<(B_ * 3584) / 256, 256, 0, stream>>>(gpart, positions, ctab, stab, qbuf, pk, pv);
  // launched twice on purpose this round: dur_R6 - others ~= 2 * t_attn (attribution experiment)
  k_attn<<<dim3(B_ * NKV, NCHUNK), 128, 0, stream>>>(kc, vc, bt, qbuf, pk, pv, ctab, stab, apart);
  k_attn<<<dim3(B_ * NKV, NCHUNK), 128, 0, stream>>>(kc, vc, bt, qbuf, pk, pv, ctab, stab, apart);
  k_attn_combine<<<B_ * NKV, 512, 0, stream>>>(apart, attn);
  k_gemm_part<<<dim3(HIDDEN / 512, NSPLIT), 256, 0, stream>>>(attn, w_o, gpart, HIDDEN, HIDDEN);
  k_reduce_out<<<(B_ * HIDDEN) / 256, 256, 0, stream>>>(gpart, out);
}

// Round 7
// 291.323 us; speedup vs baseline: 1.2837x; 1.2837x over previous
//
#include <hip/hip_runtime.h>
#include <math.h>

#define B_      16
#define NH      32
#define NKV     8
#define HD      128
#define GQ      4
#define LWIN    4096
#define BS      16
#define MAXB    385
#define HIDDEN  4096
#define QKV_COLS 6144
#define TAB_N   4100
#define T_CUR   4080      // window index of the current (new) token
#define KS      64        // k-rows per gemm split slice
#define NSPLIT  64        // number of k slices (4096/KS)
#define NCHUNK  32        // 128-token chunks
#define SCALE   0.088388347648318447f   // 128^-0.5
#define LOG1E4  9.210340371976184
#define TWO_PI  6.283185307179586
#define INV_2PI 0.15915494309189535

typedef float f4v __attribute__((ext_vector_type(4)));

// ---------------- K0: trig tables + zero patched blocks ----------------
__global__ void k_table(float* __restrict__ ctab, float* __restrict__ stab,
                        float* __restrict__ pk, float* __restrict__ pv) {
  int idx = blockIdx.x * 256 + threadIdx.x;
  if (idx < 64 * (TAB_N / 4)) {
    int d = idx / (TAB_N / 4);
    int q = idx - d * (TAB_N / 4);
    int i0 = q * 4;
    double f = exp(-(double)d / 64.0 * LOG1E4);
    double a = (double)(i0 - 1) * f;
    double rev = a * INV_2PI;
    rev -= rint(rev);
    float r = (float)(rev * TWO_PI);
    float c = cosf(r), s = sinf(r);
    float ff = (float)f;
    float cf = cosf(ff), sf = sinf(ff);
    int base = d * TAB_N + i0;
    ctab[base] = c; stab[base] = s;
#pragma unroll
    for (int j = 1; j < 4; j++) {
      float cn = c * cf - s * sf;
      float sn = s * cf + c * sf;
      c = cn; s = sn;
      ctab[base + j] = c; stab[base + j] = s;
    }
  }
  int nz = B_ * NKV * HD * BS;
  for (int z = idx; z < nz; z += gridDim.x * 256) { pk[z] = 0.f; pv[z] = 0.f; }
}

// ---------------- split-K skinny GEMM partial: part[ky][b][n] ----------------
// X rows broadcast via SGPR; W as float4 per lane (1KB/wave-instr).
__global__ __launch_bounds__(128) void k_gemm_part(
    const float* __restrict__ X, const float* __restrict__ W,
    float* __restrict__ part, int K, int ncols) {
  int tid = threadIdx.x;
  int k0 = blockIdx.y * KS;
  int n4 = (blockIdx.x * 128 + tid) * 4;
  f4v acc[B_];
#pragma unroll
  for (int b = 0; b < B_; b++) acc[b] = (f4v){0.f, 0.f, 0.f, 0.f};
  const float* wp = W + (size_t)k0 * ncols + n4;
  const float* xp = X + k0;
#pragma unroll 8
  for (int kk = 0; kk < KS; kk++) {
    f4v w = __builtin_nontemporal_load((const f4v*)&wp[(size_t)kk * ncols]);
#pragma unroll
    for (int b = 0; b < B_; b++) {
      float x = xp[b * K + kk];
      acc[b][0] = fmaf(x, w[0], acc[b][0]);
      acc[b][1] = fmaf(x, w[1], acc[b][1]);
      acc[b][2] = fmaf(x, w[2], acc[b][2]);
      acc[b][3] = fmaf(x, w[3], acc[b][3]);
    }
  }
  float* pp = part + (size_t)blockIdx.y * B_ * ncols + n4;
#pragma unroll
  for (int b = 0; b < B_; b++) *(f4v*)&pp[(size_t)b * ncols] = acc[b];
}

// ------------- reduce qkv partials + RoPE + scatter q / patched k,v -------------
__global__ __launch_bounds__(256) void k_qkv_finish(
    const float* __restrict__ part, const int* __restrict__ positions,
    const float* __restrict__ ctab, const float* __restrict__ stab,
    float* __restrict__ qout, float* __restrict__ pk, float* __restrict__ pv) {
  int idx = blockIdx.x * 256 + threadIdx.x;
  int b = idx / 3584;
  int u = idx - b * 3584;
  if (b >= B_) return;
  if (u < 2560) {                       // rope pair units: h in [0,40), j in [0,64)
    int h = u >> 6, j = u & 63;
    int c1 = h * 128 + j;
    int c2 = c1 + 64;
    float s1 = 0.f, s2 = 0.f;
#pragma unroll 8
    for (int ky = 0; ky < NSPLIT; ky++) {
      const float* p = part + ((size_t)ky * B_ + b) * QKV_COLS;
      s1 += p[c1];
      s2 += p[c2];
    }
    int pos = min(positions[b], LWIN - 1);
    float c = ctab[j * TAB_N + pos + 1];
    float s = stab[j * TAB_N + pos + 1];
    float o1 = s1 * c - s2 * s;
    float o2 = s2 * c + s1 * s;
    if (h < NH) {
      qout[b * HIDDEN + c1] = o1;
      qout[b * HIDDEN + c2] = o2;
    } else {
      int kv = h - NH;
      pk[((b * NKV + kv) * HD + j) * BS] = o1;
      pk[((b * NKV + kv) * HD + j + 64) * BS] = o2;
    }
  } else {                              // v units
    int vi = u - 2560;
    int kv = vi >> 7, d = vi & 127;
    int col = 5120 + vi;
    float s = 0.f;
#pragma unroll 8
    for (int ky = 0; ky < NSPLIT; ky++)
      s += part[((size_t)ky * B_ + b) * QKV_COLS + col];
    pv[((b * NKV + kv) * HD + d) * BS] = s;
  }
}

// ------------- paged attention: block = (batch, 128-token chunk), ALL kv heads -------------
// Physical blocks of a batch are contiguous (block_tables is arange), so each
// block streams ~1MB of K and V sequentially. Wave w owns kv heads {2w, 2w+1}
// (softmax fully intra-wave); phase B threads own (d, 4 kv heads).
__global__ __launch_bounds__(256, 2) void k_attn(
    const float* __restrict__ kc, const float* __restrict__ vc,
    const int* __restrict__ bt, const float* __restrict__ qbuf,
    const float* __restrict__ pk, const float* __restrict__ pv,
    const float* __restrict__ ctab, const float* __restrict__ stab,
    float* __restrict__ partial) {
  __shared__ __align__(16) float qT[NKV][HD][GQ];   // 16 KB, broadcast reads
  __shared__ __align__(16) float p_s[32][132];      // head-major probs, 16.9 KB
  __shared__ const float* kblk[8];
  __shared__ const float* vblk[8];

  int b = blockIdx.x;
  int chunk = blockIdx.y;               // 0..31, 128 tokens
  int tid = threadIdx.x;
  int lane = tid & 63, wave = tid >> 6;

  for (int i = tid; i < NKV * HD * GQ; i += 256) {
    int kv = i >> 9, g = (i >> 7) & 3, d = i & 127;
    qT[kv][d][g] = qbuf[b * HIDDEN + i];
  }
  if (tid < 8) {
    int tb = chunk * 8 + tid;           // global 16-token block index
    if (tb == 255) {
      kblk[tid] = pk + (size_t)b * (NKV * HD * BS);
      vblk[tid] = pv + (size_t)b * (NKV * HD * BS);
    } else {
      int lg = (tb == 0) ? 0 : (129 + tb);
      size_t off = (size_t)bt[b * MAXB + lg] * (NKV * HD * BS);
      kblk[tid] = kc + off;
      vblk[tid] = vc + off;
    }
  }
  __syncthreads();

  // ---- phase A: scores for 2 kv heads per wave, d split across lane halves ----
  int kv0 = wave * 2;
  int tq = lane & 31, dh = lane >> 5;
  int t0 = chunk * 128 + tq * 4;        // first of this lane's 4 tokens
  int tbl = tq >> 2, qq = tq & 3;
  const float* kb0 = kblk[tbl] + (size_t)kv0 * (HD * BS) + qq * 4;
  const float* kb1 = kb0 + HD * BS;
  bool rot = (t0 >= 16) && (t0 < T_CUR);
  const float* ctp = ctab + t0;
  const float* stp = stab + t0;

  float sc[2][GQ][4];
#pragma unroll
  for (int kvi = 0; kvi < 2; kvi++)
#pragma unroll
    for (int g = 0; g < GQ; g++)
#pragma unroll
      for (int c = 0; c < 4; c++) sc[kvi][g][c] = 0.f;

#pragma unroll 4
  for (int dd = 0; dd < 32; dd++) {
    int d = dh * 32 + dd;
    f4v k1a = __builtin_nontemporal_load((const f4v*)(kb0 + d * BS));
    f4v k2a = __builtin_nontemporal_load((const f4v*)(kb0 + (d + 64) * BS));
    f4v k1b = __builtin_nontemporal_load((const f4v*)(kb1 + d * BS));
    f4v k2b = __builtin_nontemporal_load((const f4v*)(kb1 + (d + 64) * BS));
    float4 cv = *(const float4*)(ctp + d * TAB_N);
    float4 sv = *(const float4*)(stp + d * TAB_N);
    float4 qa1 = *(const float4*)&qT[kv0][d][0];
    float4 qa2 = *(const float4*)&qT[kv0][d + 64][0];
    float4 qb1 = *(const float4*)&qT[kv0 + 1][d][0];
    float4 qb2 = *(const float4*)&qT[kv0 + 1][d + 64][0];
    float cc[4] = {rot ? cv.x : 1.f, rot ? cv.y : 1.f, rot ? cv.z : 1.f, rot ? cv.w : 1.f};
    float ss[4] = {rot ? sv.x : 0.f, rot ? sv.y : 0.f, rot ? sv.z : 0.f, rot ? sv.w : 0.f};
    float qa1v[4] = {qa1.x, qa1.y, qa1.z, qa1.w};
    float qa2v[4] = {qa2.x, qa2.y, qa2.z, qa2.w};
    float qb1v[4] = {qb1.x, qb1.y, qb1.z, qb1.w};
    float qb2v[4] = {qb2.x, qb2.y, qb2.z, qb2.w};
#pragma unroll
    for (int c = 0; c < 4; c++) {
      float r1a = k1a[c] * cc[c] - k2a[c] * ss[c];
      float r2a = k2a[c] * cc[c] + k1a[c] * ss[c];
      float r1b = k1b[c] * cc[c] - k2b[c] * ss[c];
      float r2b = k2b[c] * cc[c] + k1b[c] * ss[c];
#pragma unroll
      for (int g = 0; g < GQ; g++) {
        sc[0][g][c] = fmaf(qa1v[g], r1a, fmaf(qa2v[g], r2a, sc[0][g][c]));
        sc[1][g][c] = fmaf(qb1v[g], r1b, fmaf(qb2v[g], r2b, sc[1][g][c]));
      }
    }
  }

  // combine d-halves (lanes l and l^32 hold the two halves)
#pragma unroll
  for (int kvi = 0; kvi < 2; kvi++)
#pragma unroll
    for (int g = 0; g < GQ; g++)
#pragma unroll
      for (int c = 0; c < 4; c++)
        sc[kvi][g][c] += __shfl_xor(sc[kvi][g][c], 32, 64);

  // scale + validity + chunk max/sum (tokens live on 32-lane groups)
  float mb[2][GQ], ls[2][GQ];
#pragma unroll
  for (int kvi = 0; kvi < 2; kvi++) {
#pragma unroll
    for (int g = 0; g < GQ; g++) {
      float m = -3e38f;
#pragma unroll
      for (int c = 0; c < 4; c++) {
        float s = (t0 + c <= T_CUR) ? sc[kvi][g][c] * SCALE : -3e38f;
        sc[kvi][g][c] = s;
        m = fmaxf(m, s);
      }
#pragma unroll
      for (int off = 1; off < 32; off <<= 1) m = fmaxf(m, __shfl_xor(m, off, 64));
      mb[kvi][g] = m;
      float l = 0.f;
#pragma unroll
      for (int c = 0; c < 4; c++) {
        float p = __expf(sc[kvi][g][c] - m);
        sc[kvi][g][c] = p;
        l += p;
      }
#pragma unroll
      for (int off = 1; off < 32; off <<= 1) l += __shfl_xor(l, off, 64);
      ls[kvi][g] = l;
    }
  }

  // write probs head-major: p_s[kv*4+g][token]
  if (dh == 0) {
#pragma unroll
    for (int kvi = 0; kvi < 2; kvi++)
#pragma unroll
      for (int g = 0; g < GQ; g++)
        *(float4*)&p_s[(kv0 + kvi) * 4 + g][tq * 4] =
            make_float4(sc[kvi][g][0], sc[kvi][g][1], sc[kvi][g][2], sc[kvi][g][3]);
  }
  if (lane == 0) {
#pragma unroll
    for (int kvi = 0; kvi < 2; kvi++) {
      float* pw = partial + ((size_t)(b * NKV + kv0 + kvi) * NCHUNK + chunk) * (GQ * 130);
#pragma unroll
      for (int g = 0; g < GQ; g++) {
        pw[g * 130 + 0] = mb[kvi][g];
        pw[g * 130 + 1] = ls[kvi][g];
      }
    }
  }
  __syncthreads();

  // ---- phase B: PV. thread owns d = tid&127 for kv heads {kvh, kvh+2, kvh+4, kvh+6} ----
  int dB = tid & 127, kvh = tid >> 7;
  float acc[4][GQ];
#pragma unroll
  for (int r = 0; r < 4; r++)
#pragma unroll
    for (int g = 0; g < GQ; g++) acc[r][g] = 0.f;

#pragma unroll 2
  for (int pb = 0; pb < 8; pb++) {
    f4v vr[4][4];
#pragma unroll
    for (int r = 0; r < 4; r++) {
      const float* vb = vblk[pb] + (size_t)(2 * r + kvh) * (HD * BS) + dB * BS;
      vr[r][0] = __builtin_nontemporal_load((const f4v*)(vb));
      vr[r][1] = __builtin_nontemporal_load((const f4v*)(vb + 4));
      vr[r][2] = __builtin_nontemporal_load((const f4v*)(vb + 8));
      vr[r][3] = __builtin_nontemporal_load((const f4v*)(vb + 12));
    }
#pragma unroll
    for (int jq = 0; jq < 4; jq++) {
#pragma unroll
      for (int r = 0; r < 4; r++) {
        int h = (2 * r + kvh) * 4;
#pragma unroll
        for (int g = 0; g < GQ; g++) {
          float4 p4 = *(const float4*)&p_s[h + g][pb * 16 + jq * 4];
          acc[r][g] = fmaf(vr[r][jq][0], p4.x,
                      fmaf(vr[r][jq][1], p4.y,
                      fmaf(vr[r][jq][2], p4.z,
                      fmaf(vr[r][jq][3], p4.w, acc[r][g]))));
        }
      }
    }
  }

#pragma unroll
  for (int r = 0; r < 4; r++) {
    int kv = 2 * r + kvh;
    float* pw = partial + ((size_t)(b * NKV + kv) * NCHUNK + chunk) * (GQ * 130);
#pragma unroll
    for (int g = 0; g < GQ; g++) pw[g * 130 + 2 + dB] = acc[r][g];
  }
}

// ---------------- combine chunk partials -> attn[b][h*128+d] ----------------
__global__ __launch_bounds__(512) void k_attn_combine(
    const float* __restrict__ partial, float* __restrict__ attn) {
  int pair = blockIdx.x;
  int tid = threadIdx.x;
  int g = tid >> 7, d = tid & 127;
  const float* pb = partial + (size_t)pair * NCHUNK * (GQ * 130) + g * 130;
  float M = -3e38f;
#pragma unroll 8
  for (int c = 0; c < NCHUNK; c++) M = fmaxf(M, pb[c * (GQ * 130)]);
  float L = 0.f, val = 0.f;
#pragma unroll 8
  for (int c = 0; c < NCHUNK; c++) {
    float m = pb[c * (GQ * 130)];
    float l = pb[c * (GQ * 130) + 1];
    float a = pb[c * (GQ * 130) + 2 + d];
    float w = __expf(m - M);
    L += l * w;
    val = fmaf(a, w, val);
  }
  int b = pair >> 3, kv = pair & 7;
  attn[b * HIDDEN + (kv * GQ + g) * HD + d] = val / L;
}

// ---------------- reduce w_o partials -> out ----------------
__global__ __launch_bounds__(256) void k_reduce_out(
    const float* __restrict__ part, float* __restrict__ out) {
  int idx = blockIdx.x * 256 + threadIdx.x;
  int b = idx >> 12, n = idx & 4095;
  float s = 0.f;
#pragma unroll 8
  for (int ky = 0; ky < NSPLIT; ky++)
    s += part[((size_t)ky * B_ + b) * HIDDEN + n];
  out[idx] = s;
}

extern "C" void kernel_launch(void* const* d_in, const int* in_sizes, int n_in,
                              void* d_out, int out_size, void* d_ws, size_t ws_size,
                              hipStream_t stream) {
  const int*   positions = (const int*)d_in[0];
  const float* hs        = (const float*)d_in[1];
  const float* kc        = (const float*)d_in[2];
  const float* vc        = (const float*)d_in[3];
  const int*   bt        = (const int*)d_in[4];
  const float* w_qkv     = (const float*)d_in[6];
  const float* w_o       = (const float*)d_in[7];
  float* out = (float*)d_out;

  float* ws    = (float*)d_ws;
  float* ctab  = ws;                    // 262400
  float* stab  = ctab + 262400;         // 262400
  float* pk    = stab + 262400;         // 262144
  float* pv    = pk + 262144;           // 262144
  float* qbuf  = pv + 262144;           // 65536
  float* apart = qbuf + 65536;          // 128*32*520 = 2129920
  float* attn  = apart + 2129920;       // 65536
  float* gpart = attn + 65536;          // 64*16*6144 = 6291456

  k_table<<<257, 256, 0, stream>>>(ctab, stab, pk, pv);
  k_gemm_part<<<dim3(QKV_COLS / 512, NSPLIT), 128, 0, stream>>>(hs, w_qkv, gpart, HIDDEN, QKV_COLS);
  k_qkv_finish<<<(B_ * 3584) / 256, 256, 0, stream>>>(gpart, positions, ctab, stab, qbuf, pk, pv);
  k_attn<<<dim3(B_, NCHUNK), 256, 0, stream>>>(kc, vc, bt, qbuf, pk, pv, ctab, stab, apart);
  k_attn_combine<<<B_ * NKV, 512, 0, stream>>>(apart, attn);
  k_gemm_part<<<dim3(HIDDEN / 512, NSPLIT), 128, 0, stream>>>(attn, w_o, gpart, HIDDEN, HIDDEN);
  k_reduce_out<<<(B_ * HIDDEN) / 256, 256, 0, stream>>>(gpart, out);
}